// Round 11
// baseline (131.386 us; speedup 1.0000x reference)
//
#include <hip/hip_runtime.h>

typedef float v2f    __attribute__((ext_vector_type(2)));
typedef float f32x16 __attribute__((ext_vector_type(16)));
typedef __bf16 bf16x8 __attribute__((ext_vector_type(8)));

#define H 512
#define W 512
#define XH 513
#define L2E 1.4426950408889634f

// ws dword layout:
// [0, 2048):     A-frags [mf][t][lane][4 dwords]  (mf in {0,1}, t 0..3, lane 0..63)
// [2048, 3072):  delta[pat-1][128] f32 indexed by MFMA row r, pat 1..8
#define WS_DELTA 2048

// row r (0..127) -> channel (q, j):
//   q = (r&1) + 2*((r>>2)&1);  j = ((r>>1)&1) + 2*((r>>3)&3) + 8*(r>>5)
__device__ inline void row2ch(int r, int& q, int& j) {
  q = (r & 1) + 2 * ((r >> 2) & 1);
  j = ((r >> 1) & 1) + 2 * ((r >> 3) & 3) + 8 * (r >> 5);
}

__device__ inline unsigned bf16_rne(float f) {
  unsigned u = __float_as_uint(f);
  return (u + 0x7FFFu + ((u >> 16) & 1u)) >> 16;
}

__device__ inline unsigned cvtpk(float lo, float hi_) {
  unsigned r;
  asm("v_cvt_pk_bf16_f32 %0, %1, %2" : "=v"(r) : "v"(lo), "v"(hi_));
  return r;
}

__global__ __launch_bounds__(1024)
void prep_kernel(const float* comp_w, const float* comp_b,
                 const float* enc_w, const float* enc_b,
                 unsigned* ws) {
  __shared__ float sWe[900];   // L2E * Weff[o][tap]
  __shared__ float sBc[900];   // L2E * Bc[o][tap]
  int t = threadIdx.x;
  if (t < 900) {
    int o = t / 9, tap = t % 9;
    float sw = 0.f, sb = 0.f;
    for (int c = 0; c < 64; ++c) {
      float e = enc_w[(o * 64 + c) * 9 + tap];
      sw += e * comp_w[c];
      sb += e * comp_b[c];
    }
    sWe[t] = sw * L2E;
    sBc[t] = sb * L2E;
  }
  __syncthreads();
  // A-frag pack: one thread per MFMA row r (128; rows with j>=25 all-zero)
  if (t < 128) {
    int r = t, q, j;
    row2ch(r, q, j);
    unsigned k1[16], k2[16];
    #pragma unroll
    for (int k = 0; k < 16; ++k) { k1[k] = 0; k2[k] = 0; }
    if (j < 25) {
      int o = j * 4 + q;
      unsigned wh[9], wl[9];
      float base = enc_b[o] * L2E;
      for (int tap = 0; tap < 9; ++tap) base += sBc[o * 9 + tap];
      for (int tap = 0; tap < 9; ++tap) {
        float wf = sWe[o * 9 + tap];
        unsigned h = bf16_rne(wf);
        wh[tap] = h;
        wl[tap] = bf16_rne(wf - __uint_as_float(h << 16));
      }
      unsigned bh = bf16_rne(base);
      unsigned bl = bf16_rne(base - __uint_as_float(bh << 16));
      // MFMA#1 A: k0-8 = Wh taps, k9 = base_h, k10-15 = Wh taps 0-5
      for (int tap = 0; tap < 9; ++tap) k1[tap] = wh[tap];
      k1[9] = bh;
      for (int tap = 0; tap < 6; ++tap) k1[10 + tap] = wh[tap];
      // MFMA#2 A: k0-2 = Wh taps 6-8, k3-11 = Wl taps 0-8, k12 = base_l
      for (int tap = 0; tap < 3; ++tap) k2[tap] = wh[6 + tap];
      for (int tap = 0; tap < 9; ++tap) k2[3 + tap] = wl[tap];
      k2[12] = bl;
    }
    int tt = r >> 5, m = r & 31;
    for (int kh = 0; kh < 2; ++kh) {
      int lane = m + 32 * kh;
      for (int d = 0; d < 4; ++d) {
        int k = kh * 8 + d * 2;
        ws[((0 * 4 + tt) * 64 + lane) * 4 + d] = k1[k] | (k1[k + 1] << 16);
        ws[((1 * 4 + tt) * 64 + lane) * 4 + d] = k2[k] | (k2[k + 1] << 16);
      }
    }
  }
  // border delta table by row: delta[pat-1][r] = -sum of invalid-tap Bc
  if (t < 1024) {
    int pat = (t >> 7) + 1, r = t & 127, q, j;
    row2ch(r, q, j);
    float dv = 0.f;
    if (j < 25) {
      int o = j * 4 + q;
      int ph = pat / 3, pw_ = pat % 3;
      for (int tap = 0; tap < 9; ++tap) {
        int dr = tap / 3, dc = tap % 3;
        bool bad = (ph == 1 && dr == 0) || (ph == 2 && dr == 2) ||
                   (pw_ == 1 && dc == 0) || (pw_ == 2 && dc == 2);
        if (bad) dv -= sBc[o * 9 + tap];
      }
    }
    ((float*)ws)[WS_DELTA + t] = dv;
  }
}

__global__ __launch_bounds__(256, 4)
void carafe_kernel(const float* x, const float* conv_w, const float* conv_b,
                   const unsigned* ws, float* out) {
  __shared__ float sF[36][36];
  __shared__ float sDelta[8][128];

  int tid = threadIdx.x;
  int n = blockIdx.z;
  int h0 = blockIdx.y * 32, w0 = blockIdx.x * 32;

  float w00 = conv_w[0], w01 = conv_w[1], w10 = conv_w[2], w11 = conv_w[3];
  float cb = conv_b[0];
  const float* xn = x + (size_t)n * XH * XH;

  for (int i = tid; i < 36 * 36; i += 256) {
    int r = i / 36, c = i - r * 36;
    int hh = h0 - 2 + r, ww = w0 - 2 + c;
    float v = 0.f;
    if (hh >= 0 && hh < H && ww >= 0 && ww < W) {
      const float* p = xn + (size_t)hh * XH + ww;
      v = cb + w00 * p[0] + w01 * p[1] + w10 * p[XH] + w11 * p[XH + 1];
    }
    sF[r][c] = v;
  }
  bool borderblk = (blockIdx.x == 0) | (blockIdx.x == 15) |
                   (blockIdx.y == 0) | (blockIdx.y == 15);
  if (borderblk)
    for (int i = tid; i < 1024; i += 256)
      ((float*)sDelta)[i] = ((const float*)ws)[WS_DELTA + i];

  int lane = tid & 63, wid = tid >> 6;
  int pc = lane & 31, hi = lane >> 5;

  int4 A1[4], A2[4];
  #pragma unroll
  for (int t = 0; t < 4; ++t) {
    A1[t] = *(const int4*)(ws + ((0 * 4 + t) * 64 + lane) * 4);
    A2[t] = *(const int4*)(ws + ((1 * 4 + t) * 64 + lane) * 4);
  }
  __syncthreads();

  int R0 = wid * 8;
  int wx = w0 + pc;
  float one = 1.0f;

  // patch: p[i][j] = feat(h0 + R0 + rr - 2 + i, wx - 2 + j)
  float p[5][5];
  #pragma unroll
  for (int i = 0; i < 5; ++i)
    #pragma unroll
    for (int j = 0; j < 5; ++j)
      p[i][j] = sF[R0 + i][pc + j];

  const f32x16 zeroacc = {0.f};
  int pwp = (wx == 0) ? 1 : ((wx == W - 1) ? 2 : 0);

  #pragma unroll
  for (int rr = 0; rr < 8; ++rr) {
    int hpx = h0 + R0 + rr;

    // ---- B-frag build (bf16 hi/lo compensated, R8-verified packing) ----
    float t0 = p[1][1], t1 = p[1][2], t2 = p[1][3];
    float t3 = p[2][1], t4 = p[2][2], t5 = p[2][3];
    float t6 = p[3][1], t7 = p[3][2], t8 = p[3][3];
    unsigned d01 = cvtpk(t0, t1), d23 = cvtpk(t2, t3);
    unsigned d45 = cvtpk(t4, t5), d67 = cvtpk(t6, t7);
    unsigned d8x = cvtpk(t8, one);
    float fl0 = t0 - __uint_as_float(d01 << 16);
    float fl1 = t1 - __uint_as_float(d01 & 0xFFFF0000u);
    float fl2 = t2 - __uint_as_float(d23 << 16);
    float fl3 = t3 - __uint_as_float(d23 & 0xFFFF0000u);
    float fl4 = t4 - __uint_as_float(d45 << 16);
    float fl5 = t5 - __uint_as_float(d45 & 0xFFFF0000u);
    float fl6 = t6 - __uint_as_float(d67 << 16);
    float fl7 = t7 - __uint_as_float(d67 & 0xFFFF0000u);
    float fl8 = t8 - __uint_as_float(d8x << 16);
    unsigned l01 = cvtpk(fl0, fl1), l23 = cvtpk(fl2, fl3);
    unsigned l45 = cvtpk(fl4, fl5), l67 = cvtpk(fl6, fl7);

    int4 b1, b2;
    b1.x = hi ? d8x : d01;
    b1.y = hi ? l01 : d23;
    b1.z = hi ? l23 : d45;
    b1.w = hi ? l45 : d67;
    b2.x = hi ? cvtpk(t5, t6) : l67;
    b2.y = hi ? cvtpk(t7, t8) : cvtpk(fl8, t0);
    b2.z = hi ? 0x00003F80u : cvtpk(t1, t2);
    b2.w = hi ? 0u : cvtpk(t3, t4);

    // ---- border pattern ----
    int ph = (hpx == 0) ? 1 : ((hpx == H - 1) ? 2 : 0);
    int pat = ph * 3 + pwp;
    bool anyb = __any(pat != 0);

    // ---- per-t: MFMA pair -> fix -> softmax walk (one acc live) ----
    v2f sP0 = {0.f, 0.f}, aP0 = {0.f, 0.f};
    v2f sP1 = {0.f, 0.f}, aP1 = {0.f, 0.f};
    #pragma unroll
    for (int t = 0; t < 4; ++t) {
      f32x16 acc = __builtin_amdgcn_mfma_f32_32x32x16_bf16(
          __builtin_bit_cast(bf16x8, A1[t]), __builtin_bit_cast(bf16x8, b1),
          zeroacc, 0, 0, 0);
      acc = __builtin_amdgcn_mfma_f32_32x32x16_bf16(
          __builtin_bit_cast(bf16x8, A2[t]), __builtin_bit_cast(bf16x8, b2),
          acc, 0, 0, 0);
      if (anyb && pat != 0) {
        const float* dl = &sDelta[pat - 1][4 * hi];
        #pragma unroll
        for (int g = 0; g < 16; ++g) {
          if (t == 3 && g > 1) continue;
          acc[g] += dl[(g & 3) + 8 * (g >> 2) + 32 * t];
        }
      }
      #pragma unroll
      for (int jl = 0; jl < 8; ++jl) {
        if (t == 3 && jl > 0) continue;
        int j = 8 * t + jl;
        v2f e;
        e.x = __builtin_amdgcn_exp2f(acc[2 * jl + 0]);
        e.y = __builtin_amdgcn_exp2f(acc[2 * jl + 1]);
        float fj = p[j / 5][j % 5];
        if (t & 1) { sP1 += e; aP1 += e * fj; }
        else       { sP0 += e; aP0 += e * fj; }
      }
    }
    v2f s01 = sP0 + sP1;
    v2f a01 = aP0 + aP1;

    float2 res;
    res.x = a01.x * __builtin_amdgcn_rcpf(s01.x);
    res.y = a01.y * __builtin_amdgcn_rcpf(s01.y);
    float* prow = out + ((size_t)n * 1024 + 2 * hpx + hi) * 1024 + 2 * wx;
    *(float2*)prow = res;

    // ---- roll patch down one row ----
    if (rr < 7) {
      #pragma unroll
      for (int i = 0; i < 4; ++i)
        #pragma unroll
        for (int j = 0; j < 5; ++j)
          p[i][j] = p[i + 1][j];
      #pragma unroll
      for (int j = 0; j < 5; ++j)
        p[4][j] = sF[R0 + rr + 5][pc + j];
    }
  }
}

extern "C" void kernel_launch(void* const* d_in, const int* in_sizes, int n_in,
                              void* d_out, int out_size, void* d_ws, size_t ws_size,
                              hipStream_t stream) {
  const float* x      = (const float*)d_in[0];
  const float* conv_w = (const float*)d_in[1];
  const float* conv_b = (const float*)d_in[2];
  const float* comp_w = (const float*)d_in[3];
  const float* comp_b = (const float*)d_in[4];
  const float* enc_w  = (const float*)d_in[5];
  const float* enc_b  = (const float*)d_in[6];
  float* out = (float*)d_out;
  unsigned* ws = (unsigned*)d_ws;

  prep_kernel<<<1, 1024, 0, stream>>>(comp_w, comp_b, enc_w, enc_b, ws);
  carafe_kernel<<<dim3(16, 16, 8), 256, 0, stream>>>(x, conv_w, conv_b, ws, out);
}

// Round 12
// 67.553 us; speedup vs baseline: 1.9449x; 1.9449x over previous
//
#include <hip/hip_runtime.h>

typedef float v2f    __attribute__((ext_vector_type(2)));
typedef float f32x16 __attribute__((ext_vector_type(16)));
typedef __bf16 bf16x8 __attribute__((ext_vector_type(8)));

#define H 512
#define W 512
#define XH 513
#define L2E 1.4426950408889634f

// ws dword layout:
// [0, 2048):     A-frags [mf][t][lane][4 dwords]  (mf in {0,1}, t 0..3, lane 0..63)
// [2048, 3072):  delta[pat-1][128] f32 indexed by MFMA row r, pat 1..8
#define WS_DELTA 2048

// row r (0..127) -> channel (q, j):
//   q = (r&1) + 2*((r>>2)&1);  j = ((r>>1)&1) + 2*((r>>3)&3) + 8*(r>>5)
__device__ inline void row2ch(int r, int& q, int& j) {
  q = (r & 1) + 2 * ((r >> 2) & 1);
  j = ((r >> 1) & 1) + 2 * ((r >> 3) & 3) + 8 * (r >> 5);
}

__device__ inline unsigned bf16_rne(float f) {
  unsigned u = __float_as_uint(f);
  return (u + 0x7FFFu + ((u >> 16) & 1u)) >> 16;
}

__device__ inline unsigned cvtpk(float lo, float hi_) {
  unsigned r;
  asm("v_cvt_pk_bf16_f32 %0, %1, %2" : "=v"(r) : "v"(lo), "v"(hi_));
  return r;
}

__global__ __launch_bounds__(1024)
void prep_kernel(const float* comp_w, const float* comp_b,
                 const float* enc_w, const float* enc_b,
                 unsigned* ws) {
  __shared__ float sWe[900];   // L2E * Weff[o][tap]
  __shared__ float sBc[900];   // L2E * Bc[o][tap]
  int t = threadIdx.x;
  if (t < 900) {
    int o = t / 9, tap = t % 9;
    float sw = 0.f, sb = 0.f;
    for (int c = 0; c < 64; ++c) {
      float e = enc_w[(o * 64 + c) * 9 + tap];
      sw += e * comp_w[c];
      sb += e * comp_b[c];
    }
    sWe[t] = sw * L2E;
    sBc[t] = sb * L2E;
  }
  __syncthreads();
  // A-frag pack: one thread per MFMA row r (128; rows with j>=25 all-zero)
  if (t < 128) {
    int r = t, q, j;
    row2ch(r, q, j);
    unsigned k1[16], k2[16];
    #pragma unroll
    for (int k = 0; k < 16; ++k) { k1[k] = 0; k2[k] = 0; }
    if (j < 25) {
      int o = j * 4 + q;
      unsigned wh[9], wl[9];
      float base = enc_b[o] * L2E;
      for (int tap = 0; tap < 9; ++tap) base += sBc[o * 9 + tap];
      for (int tap = 0; tap < 9; ++tap) {
        float wf = sWe[o * 9 + tap];
        unsigned h = bf16_rne(wf);
        wh[tap] = h;
        wl[tap] = bf16_rne(wf - __uint_as_float(h << 16));
      }
      unsigned bh = bf16_rne(base);
      unsigned bl = bf16_rne(base - __uint_as_float(bh << 16));
      // MFMA#1 A: k0-8 = Wh taps, k9 = base_h, k10-15 = Wh taps 0-5
      for (int tap = 0; tap < 9; ++tap) k1[tap] = wh[tap];
      k1[9] = bh;
      for (int tap = 0; tap < 6; ++tap) k1[10 + tap] = wh[tap];
      // MFMA#2 A: k0-2 = Wh taps 6-8, k3-11 = Wl taps 0-8, k12 = base_l
      for (int tap = 0; tap < 3; ++tap) k2[tap] = wh[6 + tap];
      for (int tap = 0; tap < 9; ++tap) k2[3 + tap] = wl[tap];
      k2[12] = bl;
    }
    int tt = r >> 5, m = r & 31;
    for (int kh = 0; kh < 2; ++kh) {
      int lane = m + 32 * kh;
      for (int d = 0; d < 4; ++d) {
        int k = kh * 8 + d * 2;
        ws[((0 * 4 + tt) * 64 + lane) * 4 + d] = k1[k] | (k1[k + 1] << 16);
        ws[((1 * 4 + tt) * 64 + lane) * 4 + d] = k2[k] | (k2[k + 1] << 16);
      }
    }
  }
  // border delta table by row: delta[pat-1][r] = -sum of invalid-tap Bc
  if (t < 1024) {
    int pat = (t >> 7) + 1, r = t & 127, q, j;
    row2ch(r, q, j);
    float dv = 0.f;
    if (j < 25) {
      int o = j * 4 + q;
      int ph = pat / 3, pw_ = pat % 3;
      for (int tap = 0; tap < 9; ++tap) {
        int dr = tap / 3, dc = tap % 3;
        bool bad = (ph == 1 && dr == 0) || (ph == 2 && dr == 2) ||
                   (pw_ == 1 && dc == 0) || (pw_ == 2 && dc == 2);
        if (bad) dv -= sBc[o * 9 + tap];
      }
    }
    ((float*)ws)[WS_DELTA + t] = dv;
  }
}

__global__ __launch_bounds__(256, 4)
void carafe_kernel(const float* x, const float* conv_w, const float* conv_b,
                   const unsigned* ws, float* out) {
  // sA FIRST: A-frags [mf*4+t][lane] as int4 -> byte offset ((mf*4+t)*64+lane)*16
  __shared__ __align__(16) int4 sA[512];
  __shared__ float sF[36][36];
  __shared__ float sDelta[8][128];

  int tid = threadIdx.x;
  int n = blockIdx.z;
  int h0 = blockIdx.y * 32, w0 = blockIdx.x * 32;

  // stage A-frags (2048 dwords = 512 int4)
  for (int i = tid; i < 512; i += 256)
    sA[i] = ((const int4*)ws)[i];

  float w00 = conv_w[0], w01 = conv_w[1], w10 = conv_w[2], w11 = conv_w[3];
  float cb = conv_b[0];
  const float* xn = x + (size_t)n * XH * XH;

  for (int i = tid; i < 36 * 36; i += 256) {
    int r = i / 36, c = i - r * 36;
    int hh = h0 - 2 + r, ww = w0 - 2 + c;
    float v = 0.f;
    if (hh >= 0 && hh < H && ww >= 0 && ww < W) {
      const float* p = xn + (size_t)hh * XH + ww;
      v = cb + w00 * p[0] + w01 * p[1] + w10 * p[XH] + w11 * p[XH + 1];
    }
    sF[r][c] = v;
  }
  bool borderblk = (blockIdx.x == 0) | (blockIdx.x == 15) |
                   (blockIdx.y == 0) | (blockIdx.y == 15);
  if (borderblk)
    for (int i = tid; i < 1024; i += 256)
      ((float*)sDelta)[i] = ((const float*)ws)[WS_DELTA + i];

  int lane = tid & 63, wid = tid >> 6;
  int pc = lane & 31, hi = lane >> 5;

  __syncthreads();

  // LDS byte address of this lane's A-frag slot (sA is at LDS offset 0)
  unsigned abase = (unsigned)(size_t)(&sA[0]) + (unsigned)lane * 16u;

  int R0 = wid * 8;
  int wx = w0 + pc;
  float one = 1.0f;

  // patch: p[i][j] = feat(h0 + R0 + rr - 2 + i, wx - 2 + j)
  float p[5][5];
  #pragma unroll
  for (int i = 0; i < 5; ++i)
    #pragma unroll
    for (int j = 0; j < 5; ++j)
      p[i][j] = sF[R0 + i][pc + j];

  const f32x16 zeroacc = {0.f};
  int pwp = (wx == 0) ? 1 : ((wx == W - 1) ? 2 : 0);

  #pragma unroll
  for (int rr = 0; rr < 8; ++rr) {
    int hpx = h0 + R0 + rr;

    // ---- B-frag build (bf16 hi/lo compensated, R8-verified packing) ----
    float t0 = p[1][1], t1 = p[1][2], t2 = p[1][3];
    float t3 = p[2][1], t4 = p[2][2], t5 = p[2][3];
    float t6 = p[3][1], t7 = p[3][2], t8 = p[3][3];
    unsigned d01 = cvtpk(t0, t1), d23 = cvtpk(t2, t3);
    unsigned d45 = cvtpk(t4, t5), d67 = cvtpk(t6, t7);
    unsigned d8x = cvtpk(t8, one);
    float fl0 = t0 - __uint_as_float(d01 << 16);
    float fl1 = t1 - __uint_as_float(d01 & 0xFFFF0000u);
    float fl2 = t2 - __uint_as_float(d23 << 16);
    float fl3 = t3 - __uint_as_float(d23 & 0xFFFF0000u);
    float fl4 = t4 - __uint_as_float(d45 << 16);
    float fl5 = t5 - __uint_as_float(d45 & 0xFFFF0000u);
    float fl6 = t6 - __uint_as_float(d67 << 16);
    float fl7 = t7 - __uint_as_float(d67 & 0xFFFF0000u);
    float fl8 = t8 - __uint_as_float(d8x << 16);
    unsigned l01 = cvtpk(fl0, fl1), l23 = cvtpk(fl2, fl3);
    unsigned l45 = cvtpk(fl4, fl5), l67 = cvtpk(fl6, fl7);

    int4 b1, b2;
    b1.x = hi ? d8x : d01;
    b1.y = hi ? l01 : d23;
    b1.z = hi ? l23 : d45;
    b1.w = hi ? l45 : d67;
    b2.x = hi ? cvtpk(t5, t6) : l67;
    b2.y = hi ? cvtpk(t7, t8) : cvtpk(fl8, t0);
    b2.z = hi ? 0x00003F80u : cvtpk(t1, t2);
    b2.w = hi ? 0u : cvtpk(t3, t4);

    // ---- border pattern ----
    int ph = (hpx == 0) ? 1 : ((hpx == H - 1) ? 2 : 0);
    int pat = ph * 3 + pwp;
    bool anyb = __any(pat != 0);

    // ---- per-t: LDS A-frags -> MFMA pair -> fix -> softmax walk ----
    v2f sP0 = {0.f, 0.f}, aP0 = {0.f, 0.f};
    v2f sP1 = {0.f, 0.f}, aP1 = {0.f, 0.f};
    #pragma unroll
    for (int t = 0; t < 4; ++t) {
      unsigned at = abase + (unsigned)(t * 1024);
      int4 a1, a2;
      asm volatile("ds_read_b128 %0, %2\n\t"
                   "ds_read_b128 %1, %2 offset:4096\n\t"
                   "s_waitcnt lgkmcnt(0)"
                   : "=v"(a1), "=v"(a2) : "v"(at));
      f32x16 acc = __builtin_amdgcn_mfma_f32_32x32x16_bf16(
          __builtin_bit_cast(bf16x8, a1), __builtin_bit_cast(bf16x8, b1),
          zeroacc, 0, 0, 0);
      acc = __builtin_amdgcn_mfma_f32_32x32x16_bf16(
          __builtin_bit_cast(bf16x8, a2), __builtin_bit_cast(bf16x8, b2),
          acc, 0, 0, 0);
      if (anyb && pat != 0) {
        const float* dl = &sDelta[pat - 1][4 * hi];
        #pragma unroll
        for (int g = 0; g < 16; ++g) {
          if (t == 3 && g > 1) continue;
          acc[g] += dl[(g & 3) + 8 * (g >> 2) + 32 * t];
        }
      }
      #pragma unroll
      for (int jl = 0; jl < 8; ++jl) {
        if (t == 3 && jl > 0) continue;
        int j = 8 * t + jl;
        v2f e;
        e.x = __builtin_amdgcn_exp2f(acc[2 * jl + 0]);
        e.y = __builtin_amdgcn_exp2f(acc[2 * jl + 1]);
        float fj = p[j / 5][j % 5];
        if (t & 1) { sP1 += e; aP1 += e * fj; }
        else       { sP0 += e; aP0 += e * fj; }
      }
    }
    v2f s01 = sP0 + sP1;
    v2f a01 = aP0 + aP1;

    float2 res;
    res.x = a01.x * __builtin_amdgcn_rcpf(s01.x);
    res.y = a01.y * __builtin_amdgcn_rcpf(s01.y);
    float* prow = out + ((size_t)n * 1024 + 2 * hpx + hi) * 1024 + 2 * wx;
    *(float2*)prow = res;

    // ---- roll patch down one row ----
    if (rr < 7) {
      #pragma unroll
      for (int i = 0; i < 4; ++i)
        #pragma unroll
        for (int j = 0; j < 5; ++j)
          p[i][j] = p[i + 1][j];
      #pragma unroll
      for (int j = 0; j < 5; ++j)
        p[4][j] = sF[R0 + rr + 5][pc + j];
    }
  }
}

extern "C" void kernel_launch(void* const* d_in, const int* in_sizes, int n_in,
                              void* d_out, int out_size, void* d_ws, size_t ws_size,
                              hipStream_t stream) {
  const float* x      = (const float*)d_in[0];
  const float* conv_w = (const float*)d_in[1];
  const float* conv_b = (const float*)d_in[2];
  const float* comp_w = (const float*)d_in[3];
  const float* comp_b = (const float*)d_in[4];
  const float* enc_w  = (const float*)d_in[5];
  const float* enc_b  = (const float*)d_in[6];
  float* out = (float*)d_out;
  unsigned* ws = (unsigned*)d_ws;

  prep_kernel<<<1, 1024, 0, stream>>>(comp_w, comp_b, enc_w, enc_b, ws);
  carafe_kernel<<<dim3(16, 16, 8), 256, 0, stream>>>(x, conv_w, conv_b, ws, out);
}

// Round 13
// 63.420 us; speedup vs baseline: 2.0717x; 1.0652x over previous
//
#include <hip/hip_runtime.h>

typedef float v2f    __attribute__((ext_vector_type(2)));
typedef float f32x16 __attribute__((ext_vector_type(16)));
typedef __bf16 bf16x8 __attribute__((ext_vector_type(8)));

#define H 512
#define W 512
#define XH 513
#define L2E 1.4426950408889634f

// ws dword layout:
// [0, 2048):     A-frags [mf][t][lane][4 dwords]  (mf in {0,1}, t 0..3, lane 0..63)
// [2048, 3072):  delta[pat-1][128] f32 indexed by MFMA row r, pat 1..8
#define WS_DELTA 2048

// row r (0..127) -> channel (q, j):
//   q = (r&1) + 2*((r>>2)&1);  j = ((r>>1)&1) + 2*((r>>3)&3) + 8*(r>>5)
__device__ inline void row2ch(int r, int& q, int& j) {
  q = (r & 1) + 2 * ((r >> 2) & 1);
  j = ((r >> 1) & 1) + 2 * ((r >> 3) & 3) + 8 * (r >> 5);
}

__device__ inline unsigned bf16_rne(float f) {
  unsigned u = __float_as_uint(f);
  return (u + 0x7FFFu + ((u >> 16) & 1u)) >> 16;
}

__device__ inline unsigned cvtpk(float lo, float hi_) {
  unsigned r;
  asm("v_cvt_pk_bf16_f32 %0, %1, %2" : "=v"(r) : "v"(lo), "v"(hi_));
  return r;
}

__global__ __launch_bounds__(1024)
void prep_kernel(const float* comp_w, const float* comp_b,
                 const float* enc_w, const float* enc_b,
                 unsigned* ws) {
  __shared__ float sWe[900];   // L2E * Weff[o][tap]
  __shared__ float sBc[900];   // L2E * Bc[o][tap]
  int t = threadIdx.x;
  if (t < 900) {
    int o = t / 9, tap = t % 9;
    float sw = 0.f, sb = 0.f;
    for (int c = 0; c < 64; ++c) {
      float e = enc_w[(o * 64 + c) * 9 + tap];
      sw += e * comp_w[c];
      sb += e * comp_b[c];
    }
    sWe[t] = sw * L2E;
    sBc[t] = sb * L2E;
  }
  __syncthreads();
  // A-frag pack: one thread per MFMA row r (128; rows with j>=25 all-zero)
  if (t < 128) {
    int r = t, q, j;
    row2ch(r, q, j);
    unsigned k1[16], k2[16];
    #pragma unroll
    for (int k = 0; k < 16; ++k) { k1[k] = 0; k2[k] = 0; }
    if (j < 25) {
      int o = j * 4 + q;
      unsigned wh[9], wl[9];
      float base = enc_b[o] * L2E;
      for (int tap = 0; tap < 9; ++tap) base += sBc[o * 9 + tap];
      for (int tap = 0; tap < 9; ++tap) {
        float wf = sWe[o * 9 + tap];
        unsigned h = bf16_rne(wf);
        wh[tap] = h;
        wl[tap] = bf16_rne(wf - __uint_as_float(h << 16));
      }
      unsigned bh = bf16_rne(base);
      unsigned bl = bf16_rne(base - __uint_as_float(bh << 16));
      // MFMA#1 A: k0-8 = Wh taps, k9 = base_h, k10-15 = Wh taps 0-5
      for (int tap = 0; tap < 9; ++tap) k1[tap] = wh[tap];
      k1[9] = bh;
      for (int tap = 0; tap < 6; ++tap) k1[10 + tap] = wh[tap];
      // MFMA#2 A: k0-2 = Wh taps 6-8, k3-11 = Wl taps 0-8, k12 = base_l
      for (int tap = 0; tap < 3; ++tap) k2[tap] = wh[6 + tap];
      for (int tap = 0; tap < 9; ++tap) k2[3 + tap] = wl[tap];
      k2[12] = bl;
    }
    int tt = r >> 5, m = r & 31;
    for (int kh = 0; kh < 2; ++kh) {
      int lane = m + 32 * kh;
      for (int d = 0; d < 4; ++d) {
        int k = kh * 8 + d * 2;
        ws[((0 * 4 + tt) * 64 + lane) * 4 + d] = k1[k] | (k1[k + 1] << 16);
        ws[((1 * 4 + tt) * 64 + lane) * 4 + d] = k2[k] | (k2[k + 1] << 16);
      }
    }
  }
  // border delta table by row: delta[pat-1][r] = -sum of invalid-tap Bc
  if (t < 1024) {
    int pat = (t >> 7) + 1, r = t & 127, q, j;
    row2ch(r, q, j);
    float dv = 0.f;
    if (j < 25) {
      int o = j * 4 + q;
      int ph = pat / 3, pw_ = pat % 3;
      for (int tap = 0; tap < 9; ++tap) {
        int dr = tap / 3, dc = tap % 3;
        bool bad = (ph == 1 && dr == 0) || (ph == 2 && dr == 2) ||
                   (pw_ == 1 && dc == 0) || (pw_ == 2 && dc == 2);
        if (bad) dv -= sBc[o * 9 + tap];
      }
    }
    ((float*)ws)[WS_DELTA + t] = dv;
  }
}

__global__ __launch_bounds__(256, 3)
void carafe_kernel(const float* x, const float* conv_w, const float* conv_b,
                   const unsigned* ws, float* out) {
  // sA FIRST: A-frags [mf*4+t][lane] as int4 -> byte offset ((mf*4+t)*64+lane)*16
  __shared__ __align__(16) int4 sA[512];
  __shared__ float sF[36][36];
  __shared__ float sDelta[8][128];

  int tid = threadIdx.x;
  int n = blockIdx.z;
  int h0 = blockIdx.y * 32, w0 = blockIdx.x * 32;

  // stage A-frags (2048 dwords = 512 int4)
  for (int i = tid; i < 512; i += 256)
    sA[i] = ((const int4*)ws)[i];

  float w00 = conv_w[0], w01 = conv_w[1], w10 = conv_w[2], w11 = conv_w[3];
  float cb = conv_b[0];
  const float* xn = x + (size_t)n * XH * XH;

  for (int i = tid; i < 36 * 36; i += 256) {
    int r = i / 36, c = i - r * 36;
    int hh = h0 - 2 + r, ww = w0 - 2 + c;
    float v = 0.f;
    if (hh >= 0 && hh < H && ww >= 0 && ww < W) {
      const float* p = xn + (size_t)hh * XH + ww;
      v = cb + w00 * p[0] + w01 * p[1] + w10 * p[XH] + w11 * p[XH + 1];
    }
    sF[r][c] = v;
  }
  bool borderblk = (blockIdx.x == 0) | (blockIdx.x == 15) |
                   (blockIdx.y == 0) | (blockIdx.y == 15);
  if (borderblk)
    for (int i = tid; i < 1024; i += 256)
      ((float*)sDelta)[i] = ((const float*)ws)[WS_DELTA + i];

  int lane = tid & 63, wid = tid >> 6;
  int pc = lane & 31, hi = lane >> 5;

  __syncthreads();

  // LDS byte address of this lane's A-frag slot (sA is at LDS offset 0)
  unsigned abase = (unsigned)(size_t)(&sA[0]) + (unsigned)lane * 16u;

  int R0 = wid * 8;
  int wx = w0 + pc;
  float one = 1.0f;

  // patch: p[i][j] = feat(h0 + R0 + rr - 2 + i, wx - 2 + j)
  float p[5][5];
  #pragma unroll
  for (int i = 0; i < 5; ++i)
    #pragma unroll
    for (int j = 0; j < 5; ++j)
      p[i][j] = sF[R0 + i][pc + j];

  const f32x16 zeroacc = {0.f};
  int pwp = (wx == 0) ? 1 : ((wx == W - 1) ? 2 : 0);

  #pragma unroll
  for (int rr = 0; rr < 8; ++rr) {
    int hpx = h0 + R0 + rr;

    // ---- B-frag build (bf16 hi/lo compensated, R8-verified packing) ----
    float t0 = p[1][1], t1 = p[1][2], t2 = p[1][3];
    float t3 = p[2][1], t4 = p[2][2], t5 = p[2][3];
    float t6 = p[3][1], t7 = p[3][2], t8 = p[3][3];
    unsigned d01 = cvtpk(t0, t1), d23 = cvtpk(t2, t3);
    unsigned d45 = cvtpk(t4, t5), d67 = cvtpk(t6, t7);
    unsigned d8x = cvtpk(t8, one);
    float fl0 = t0 - __uint_as_float(d01 << 16);
    float fl1 = t1 - __uint_as_float(d01 & 0xFFFF0000u);
    float fl2 = t2 - __uint_as_float(d23 << 16);
    float fl3 = t3 - __uint_as_float(d23 & 0xFFFF0000u);
    float fl4 = t4 - __uint_as_float(d45 << 16);
    float fl5 = t5 - __uint_as_float(d45 & 0xFFFF0000u);
    float fl6 = t6 - __uint_as_float(d67 << 16);
    float fl7 = t7 - __uint_as_float(d67 & 0xFFFF0000u);
    float fl8 = t8 - __uint_as_float(d8x << 16);
    unsigned l01 = cvtpk(fl0, fl1), l23 = cvtpk(fl2, fl3);
    unsigned l45 = cvtpk(fl4, fl5), l67 = cvtpk(fl6, fl7);

    int4 b1, b2;
    b1.x = hi ? d8x : d01;
    b1.y = hi ? l01 : d23;
    b1.z = hi ? l23 : d45;
    b1.w = hi ? l45 : d67;
    b2.x = hi ? cvtpk(t5, t6) : l67;
    b2.y = hi ? cvtpk(t7, t8) : cvtpk(fl8, t0);
    b2.z = hi ? 0x00003F80u : cvtpk(t1, t2);
    b2.w = hi ? 0u : cvtpk(t3, t4);

    // ---- border pattern ----
    int ph = (hpx == 0) ? 1 : ((hpx == H - 1) ? 2 : 0);
    int pat = ph * 3 + pwp;
    bool anyb = __any(pat != 0);

    // ---- per-t: LDS A-frags -> MFMA pair -> fix -> softmax walk ----
    v2f sP0 = {0.f, 0.f}, aP0 = {0.f, 0.f};
    v2f sP1 = {0.f, 0.f}, aP1 = {0.f, 0.f};
    #pragma unroll
    for (int t = 0; t < 4; ++t) {
      unsigned at = abase + (unsigned)(t * 1024);
      int4 a1, a2;
      asm volatile("ds_read_b128 %0, %2\n\t"
                   "ds_read_b128 %1, %2 offset:4096\n\t"
                   "s_waitcnt lgkmcnt(0)"
                   : "=v"(a1), "=v"(a2) : "v"(at));
      f32x16 acc = __builtin_amdgcn_mfma_f32_32x32x16_bf16(
          __builtin_bit_cast(bf16x8, a1), __builtin_bit_cast(bf16x8, b1),
          zeroacc, 0, 0, 0);
      acc = __builtin_amdgcn_mfma_f32_32x32x16_bf16(
          __builtin_bit_cast(bf16x8, a2), __builtin_bit_cast(bf16x8, b2),
          acc, 0, 0, 0);
      if (anyb && pat != 0) {
        const float* dl = &sDelta[pat - 1][4 * hi];
        #pragma unroll
        for (int g = 0; g < 16; ++g) {
          if (t == 3 && g > 1) continue;
          acc[g] += dl[(g & 3) + 8 * (g >> 2) + 32 * t];
        }
      }
      #pragma unroll
      for (int jl = 0; jl < 8; ++jl) {
        if (t == 3 && jl > 0) continue;
        int j = 8 * t + jl;
        v2f e;
        e.x = __builtin_amdgcn_exp2f(acc[2 * jl + 0]);
        e.y = __builtin_amdgcn_exp2f(acc[2 * jl + 1]);
        float fj = p[j / 5][j % 5];
        if (t & 1) { sP1 += e; aP1 += e * fj; }
        else       { sP0 += e; aP0 += e * fj; }
      }
    }
    v2f s01 = sP0 + sP1;
    v2f a01 = aP0 + aP1;

    float2 res;
    res.x = a01.x * __builtin_amdgcn_rcpf(s01.x);
    res.y = a01.y * __builtin_amdgcn_rcpf(s01.y);
    float* prow = out + ((size_t)n * 1024 + 2 * hpx + hi) * 1024 + 2 * wx;
    *(float2*)prow = res;

    // ---- roll patch down one row ----
    if (rr < 7) {
      #pragma unroll
      for (int i = 0; i < 4; ++i)
        #pragma unroll
        for (int j = 0; j < 5; ++j)
          p[i][j] = p[i + 1][j];
      #pragma unroll
      for (int j = 0; j < 5; ++j)
        p[4][j] = sF[R0 + rr + 5][pc + j];
    }
  }
}

extern "C" void kernel_launch(void* const* d_in, const int* in_sizes, int n_in,
                              void* d_out, int out_size, void* d_ws, size_t ws_size,
                              hipStream_t stream) {
  const float* x      = (const float*)d_in[0];
  const float* conv_w = (const float*)d_in[1];
  const float* conv_b = (const float*)d_in[2];
  const float* comp_w = (const float*)d_in[3];
  const float* comp_b = (const float*)d_in[4];
  const float* enc_w  = (const float*)d_in[5];
  const float* enc_b  = (const float*)d_in[6];
  float* out = (float*)d_out;
  unsigned* ws = (unsigned*)d_ws;

  prep_kernel<<<1, 1024, 0, stream>>>(comp_w, comp_b, enc_w, enc_b, ws);
  carafe_kernel<<<dim3(16, 16, 8), 256, 0, stream>>>(x, conv_w, conv_b, ws, out);
}

// Round 14
// 61.009 us; speedup vs baseline: 2.1536x; 1.0395x over previous
//
#include <hip/hip_runtime.h>

typedef float v2f    __attribute__((ext_vector_type(2)));
typedef float f32x16 __attribute__((ext_vector_type(16)));
typedef __bf16 bf16x8 __attribute__((ext_vector_type(8)));

#define H 512
#define W 512
#define XH 513
#define L2E 1.4426950408889634f

// ws dword layout:
// [0, 2048):     A-frags [mf][t][lane][4 dwords]  (mf in {0,1}, t 0..3, lane 0..63)
// [2048, 3072):  delta[pat-1][128] f32 indexed by MFMA row r, pat 1..8
#define WS_DELTA 2048

// row r (0..127) -> channel (q, j):
//   q = (r&1) + 2*((r>>2)&1);  j = ((r>>1)&1) + 2*((r>>3)&3) + 8*(r>>5)
__device__ inline void row2ch(int r, int& q, int& j) {
  q = (r & 1) + 2 * ((r >> 2) & 1);
  j = ((r >> 1) & 1) + 2 * ((r >> 3) & 3) + 8 * (r >> 5);
}

__device__ inline unsigned bf16_rne(float f) {
  unsigned u = __float_as_uint(f);
  return (u + 0x7FFFu + ((u >> 16) & 1u)) >> 16;
}

__device__ inline unsigned cvtpk(float lo, float hi_) {
  unsigned r;
  asm("v_cvt_pk_bf16_f32 %0, %1, %2" : "=v"(r) : "v"(lo), "v"(hi_));
  return r;
}

__global__ __launch_bounds__(1024)
void prep_kernel(const float* comp_w, const float* comp_b,
                 const float* enc_w, const float* enc_b,
                 unsigned* ws) {
  __shared__ float sWe[900];   // L2E * Weff[o][tap]
  __shared__ float sBc[900];   // L2E * Bc[o][tap]
  int t = threadIdx.x;
  if (t < 900) {
    int o = t / 9, tap = t % 9;
    float sw = 0.f, sb = 0.f;
    for (int c = 0; c < 64; ++c) {
      float e = enc_w[(o * 64 + c) * 9 + tap];
      sw += e * comp_w[c];
      sb += e * comp_b[c];
    }
    sWe[t] = sw * L2E;
    sBc[t] = sb * L2E;
  }
  __syncthreads();
  // A-frag pack: one thread per MFMA row r (128; rows with j>=25 all-zero)
  if (t < 128) {
    int r = t, q, j;
    row2ch(r, q, j);
    unsigned k1[16], k2[16];
    #pragma unroll
    for (int k = 0; k < 16; ++k) { k1[k] = 0; k2[k] = 0; }
    if (j < 25) {
      int o = j * 4 + q;
      unsigned wh[9], wl[9];
      float base = enc_b[o] * L2E;
      for (int tap = 0; tap < 9; ++tap) base += sBc[o * 9 + tap];
      for (int tap = 0; tap < 9; ++tap) {
        float wf = sWe[o * 9 + tap];
        unsigned h = bf16_rne(wf);
        wh[tap] = h;
        wl[tap] = bf16_rne(wf - __uint_as_float(h << 16));
      }
      unsigned bh = bf16_rne(base);
      unsigned bl = bf16_rne(base - __uint_as_float(bh << 16));
      // MFMA#1 A: k0-8 = Wh taps, k9 = base_h, k10-15 = Wh taps 0-5
      for (int tap = 0; tap < 9; ++tap) k1[tap] = wh[tap];
      k1[9] = bh;
      for (int tap = 0; tap < 6; ++tap) k1[10 + tap] = wh[tap];
      // MFMA#2 A: k0-2 = Wh taps 6-8, k3-11 = Wl taps 0-8, k12 = base_l
      for (int tap = 0; tap < 3; ++tap) k2[tap] = wh[6 + tap];
      for (int tap = 0; tap < 9; ++tap) k2[3 + tap] = wl[tap];
      k2[12] = bl;
    }
    int tt = r >> 5, m = r & 31;
    for (int kh = 0; kh < 2; ++kh) {
      int lane = m + 32 * kh;
      for (int d = 0; d < 4; ++d) {
        int k = kh * 8 + d * 2;
        ws[((0 * 4 + tt) * 64 + lane) * 4 + d] = k1[k] | (k1[k + 1] << 16);
        ws[((1 * 4 + tt) * 64 + lane) * 4 + d] = k2[k] | (k2[k + 1] << 16);
      }
    }
  }
  // border delta table by row: delta[pat-1][r] = -sum of invalid-tap Bc
  if (t < 1024) {
    int pat = (t >> 7) + 1, r = t & 127, q, j;
    row2ch(r, q, j);
    float dv = 0.f;
    if (j < 25) {
      int o = j * 4 + q;
      int ph = pat / 3, pw_ = pat % 3;
      for (int tap = 0; tap < 9; ++tap) {
        int dr = tap / 3, dc = tap % 3;
        bool bad = (ph == 1 && dr == 0) || (ph == 2 && dr == 2) ||
                   (pw_ == 1 && dc == 0) || (pw_ == 2 && dc == 2);
        if (bad) dv -= sBc[o * 9 + tap];
      }
    }
    ((float*)ws)[WS_DELTA + t] = dv;
  }
}

__global__ __launch_bounds__(256, 3)
void carafe_kernel(const float* x, const float* conv_w, const float* conv_b,
                   const unsigned* ws, float* out) {
  __shared__ float sF[36][36];
  __shared__ float sDelta[8][128];

  int tid = threadIdx.x;
  int n = blockIdx.z;
  int h0 = blockIdx.y * 32, w0 = blockIdx.x * 32;

  float w00 = conv_w[0], w01 = conv_w[1], w10 = conv_w[2], w11 = conv_w[3];
  float cb = conv_b[0];
  const float* xn = x + (size_t)n * XH * XH;

  for (int i = tid; i < 36 * 36; i += 256) {
    int r = i / 36, c = i - r * 36;
    int hh = h0 - 2 + r, ww = w0 - 2 + c;
    float v = 0.f;
    if (hh >= 0 && hh < H && ww >= 0 && ww < W) {
      const float* p = xn + (size_t)hh * XH + ww;
      v = cb + w00 * p[0] + w01 * p[1] + w10 * p[XH] + w11 * p[XH + 1];
    }
    sF[r][c] = v;
  }
  bool borderblk = (blockIdx.x == 0) | (blockIdx.x == 15) |
                   (blockIdx.y == 0) | (blockIdx.y == 15);
  if (borderblk)
    for (int i = tid; i < 1024; i += 256)
      ((float*)sDelta)[i] = ((const float*)ws)[WS_DELTA + i];

  int lane = tid & 63, wid = tid >> 6;
  int pc = lane & 31, hi = lane >> 5;

  int4 A1[4], A2[4];
  #pragma unroll
  for (int t = 0; t < 4; ++t) {
    A1[t] = *(const int4*)(ws + ((0 * 4 + t) * 64 + lane) * 4);
    A2[t] = *(const int4*)(ws + ((1 * 4 + t) * 64 + lane) * 4);
  }
  __syncthreads();

  int R0 = wid * 8;
  int wx = w0 + pc;
  float one = 1.0f;

  // patch: p[i][j] = feat(h0 + R0 + rr - 2 + i, wx - 2 + j)
  float p[5][5];
  #pragma unroll
  for (int i = 0; i < 5; ++i)
    #pragma unroll
    for (int j = 0; j < 5; ++j)
      p[i][j] = sF[R0 + i][pc + j];

  const f32x16 zeroacc = {0.f};
  int pwp = (wx == 0) ? 1 : ((wx == W - 1) ? 2 : 0);

  #pragma unroll
  for (int rr = 0; rr < 8; ++rr) {
    int hpx = h0 + R0 + rr;

    // ---- B-frag build (bf16 hi/lo compensated, R8-verified packing) ----
    float t0 = p[1][1], t1 = p[1][2], t2 = p[1][3];
    float t3 = p[2][1], t4 = p[2][2], t5 = p[2][3];
    float t6 = p[3][1], t7 = p[3][2], t8 = p[3][3];
    unsigned d01 = cvtpk(t0, t1), d23 = cvtpk(t2, t3);
    unsigned d45 = cvtpk(t4, t5), d67 = cvtpk(t6, t7);
    unsigned d8x = cvtpk(t8, one);
    float fl0 = t0 - __uint_as_float(d01 << 16);
    float fl1 = t1 - __uint_as_float(d01 & 0xFFFF0000u);
    float fl2 = t2 - __uint_as_float(d23 << 16);
    float fl3 = t3 - __uint_as_float(d23 & 0xFFFF0000u);
    float fl4 = t4 - __uint_as_float(d45 << 16);
    float fl5 = t5 - __uint_as_float(d45 & 0xFFFF0000u);
    float fl6 = t6 - __uint_as_float(d67 << 16);
    float fl7 = t7 - __uint_as_float(d67 & 0xFFFF0000u);
    float fl8 = t8 - __uint_as_float(d8x << 16);
    unsigned l01 = cvtpk(fl0, fl1), l23 = cvtpk(fl2, fl3);
    unsigned l45 = cvtpk(fl4, fl5), l67 = cvtpk(fl6, fl7);

    int4 b1, b2;
    b1.x = hi ? d8x : d01;
    b1.y = hi ? l01 : d23;
    b1.z = hi ? l23 : d45;
    b1.w = hi ? l45 : d67;
    b2.x = hi ? cvtpk(t5, t6) : l67;
    b2.y = hi ? cvtpk(t7, t8) : cvtpk(fl8, t0);
    b2.z = hi ? 0x00003F80u : cvtpk(t1, t2);
    b2.w = hi ? 0u : cvtpk(t3, t4);

    // ---- border pattern ----
    int ph = (hpx == 0) ? 1 : ((hpx == H - 1) ? 2 : 0);
    int pat = ph * 3 + pwp;
    bool anyb = __any(pat != 0);

    // ---- per-t: MFMA pair -> fix -> softmax walk (one acc live) ----
    v2f sP0 = {0.f, 0.f}, aP0 = {0.f, 0.f};
    v2f sP1 = {0.f, 0.f}, aP1 = {0.f, 0.f};
    #pragma unroll
    for (int t = 0; t < 4; ++t) {
      f32x16 acc = __builtin_amdgcn_mfma_f32_32x32x16_bf16(
          __builtin_bit_cast(bf16x8, A1[t]), __builtin_bit_cast(bf16x8, b1),
          zeroacc, 0, 0, 0);
      acc = __builtin_amdgcn_mfma_f32_32x32x16_bf16(
          __builtin_bit_cast(bf16x8, A2[t]), __builtin_bit_cast(bf16x8, b2),
          acc, 0, 0, 0);
      if (anyb && pat != 0) {
        const float* dl = &sDelta[pat - 1][4 * hi];
        #pragma unroll
        for (int g = 0; g < 16; ++g) {
          if (t == 3 && g > 1) continue;
          acc[g] += dl[(g & 3) + 8 * (g >> 2) + 32 * t];
        }
      }
      #pragma unroll
      for (int jl = 0; jl < 8; ++jl) {
        if (t == 3 && jl > 0) continue;
        int j = 8 * t + jl;
        v2f e;
        e.x = __builtin_amdgcn_exp2f(acc[2 * jl + 0]);
        e.y = __builtin_amdgcn_exp2f(acc[2 * jl + 1]);
        float fj = p[j / 5][j % 5];
        if (t & 1) { sP1 += e; aP1 += e * fj; }
        else       { sP0 += e; aP0 += e * fj; }
      }
    }
    v2f s01 = sP0 + sP1;
    v2f a01 = aP0 + aP1;

    float2 res;
    res.x = a01.x * __builtin_amdgcn_rcpf(s01.x);
    res.y = a01.y * __builtin_amdgcn_rcpf(s01.y);
    float* prow = out + ((size_t)n * 1024 + 2 * hpx + hi) * 1024 + 2 * wx;
    *(float2*)prow = res;

    // ---- roll patch down one row ----
    if (rr < 7) {
      #pragma unroll
      for (int i = 0; i < 4; ++i)
        #pragma unroll
        for (int j = 0; j < 5; ++j)
          p[i][j] = p[i + 1][j];
      #pragma unroll
      for (int j = 0; j < 5; ++j)
        p[4][j] = sF[R0 + rr + 5][pc + j];
    }
  }
}

extern "C" void kernel_launch(void* const* d_in, const int* in_sizes, int n_in,
                              void* d_out, int out_size, void* d_ws, size_t ws_size,
                              hipStream_t stream) {
  const float* x      = (const float*)d_in[0];
  const float* conv_w = (const float*)d_in[1];
  const float* conv_b = (const float*)d_in[2];
  const float* comp_w = (const float*)d_in[3];
  const float* comp_b = (const float*)d_in[4];
  const float* enc_w  = (const float*)d_in[5];
  const float* enc_b  = (const float*)d_in[6];
  float* out = (float*)d_out;
  unsigned* ws = (unsigned*)d_ws;

  prep_kernel<<<1, 1024, 0, stream>>>(comp_w, comp_b, enc_w, enc_b, ws);
  carafe_kernel<<<dim3(16, 16, 8), 256, 0, stream>>>(x, conv_w, conv_b, ws, out);
}